// Round 5
// baseline (153.793 us; speedup 1.0000x reference)
//
#include <hip/hip_runtime.h>

// ---------------------------------------------------------------------------
// DeltaModel: B=256, L=2048, H=V=64.
//  (1) hs/k/v/q depend only on token id (V=64) -> 64-entry tables.
//  (2) r = M_N q -> backward scan: s_j = y^{(j-1)}[c_j], y += s_j*(-G[:,c_j]),
//      r += s_j v[c_j].
//  (3) d=4 SUPERSTEP: one cross-lane round trip per 4 steps.
//        p_k = readlane(y_pre, c_k), k=0..3     (4 pipelined readlanes)
//        s0=p0; s1=fma(cf01,s0,p1);
//        s2=fma(cf12,s1,fma(cf02,s0,p2));
//        s3=fma(cf23,s2,fma(cf13,s1,fma(cf03,s0,p3)));
//        y/r += s_k * col_k  (sequential, k=0..3)
//      cf_ij = -G(c_j,c_i) = readlane(col_i.x, c_j): computed ONE superstep
//      ahead (off-chain); columns ds_read 3 supersteps ahead (4-ring, static
//      indices); token lane-selects extracted 3 supersteps ahead (SGPR ring).
//      Every fma preserves the reference nesting order -> bit-identical.
// ---------------------------------------------------------------------------

#define DPP_ADD_F32(x, ctrl, rm, bm, bc)                                      \
  (x) = (x) + __int_as_float(__builtin_amdgcn_update_dpp(                     \
            0, __float_as_int(x), (ctrl), (rm), (bm), (bc)))

__device__ __forceinline__ float wave_sum64(float x) {
  DPP_ADD_F32(x, 0x111, 0xf, 0xf, true);   // row_shr:1
  DPP_ADD_F32(x, 0x112, 0xf, 0xf, true);   // row_shr:2
  DPP_ADD_F32(x, 0x114, 0xf, 0xf, true);   // row_shr:4
  DPP_ADD_F32(x, 0x118, 0xf, 0xf, true);   // row_shr:8
  DPP_ADD_F32(x, 0x142, 0xa, 0xf, false);  // row_bcast:15
  DPP_ADD_F32(x, 0x143, 0xc, 0xf, false);  // row_bcast:31 -> lane 63 total
  return __int_as_float(__builtin_amdgcn_readlane(__float_as_int(x), 63));
}

__device__ __forceinline__ float readlane_f(float x, int lane) {
  return __int_as_float(__builtin_amdgcn_readlane(__float_as_int(x), lane));
}

// ---------------------------------------------------------------------------
// Kernel A: per-token tables k_n, v, q (weights staged in padded LDS).
// ---------------------------------------------------------------------------
__global__ __launch_bounds__(64) void build_tables(
    const float* __restrict__ embed, const float* __restrict__ W1,
    const float* __restrict__ b1, const float* __restrict__ W2,
    const float* __restrict__ b2, const float* __restrict__ gamma,
    const float* __restrict__ beta, const float* __restrict__ Wk,
    const float* __restrict__ Wv, const float* __restrict__ Wq,
    float* __restrict__ k_tab, float* __restrict__ v_tab,
    float* __restrict__ q_tab) {
  __shared__ float Wbuf[8448];
  __shared__ float e_s[64];
  __shared__ float f1_s[128];
  __shared__ float hs_s[64];
  const int tok = blockIdx.x;
  const int l = threadIdx.x;

  const float e = embed[tok * 64 + l];
  e_s[l] = e;
  for (int i = 0; i < 128; ++i) Wbuf[i * 65 + l] = W1[i * 64 + l];
  __syncthreads();

  float a0 = b1[l], a1 = b1[l + 64];
#pragma unroll
  for (int h = 0; h < 64; ++h) {
    a0 = fmaf(e_s[h], Wbuf[l * 65 + h], a0);
    a1 = fmaf(e_s[h], Wbuf[(l + 64) * 65 + h], a1);
  }
  f1_s[l] = fmaxf(a0, 0.f);
  f1_s[l + 64] = fmaxf(a1, 0.f);
  __syncthreads();

  for (int i = 0; i < 128; ++i)
    Wbuf[(i >> 1) * 131 + (i & 1) * 64 + l] = W2[i * 64 + l];
  __syncthreads();

  float acc = b2[l];
#pragma unroll
  for (int j = 0; j < 128; ++j) acc = fmaf(f1_s[j], Wbuf[l * 131 + j], acc);
  const float hval = e + acc;

  const float mu = wave_sum64(hval) * (1.f / 64.f);
  const float d = hval - mu;
  const float var = wave_sum64(d * d) * (1.f / 64.f);
  const float hs = d * (1.f / sqrtf(var + 1e-5f)) * gamma[l] + beta[l];
  hs_s[l] = hs;
  __syncthreads();

  for (int i = 0; i < 64; ++i) {
    Wbuf[i * 65 + l] = Wk[i * 64 + l];
    Wbuf[4224 + i * 65 + l] = Wv[i * 64 + l];
  }
  __syncthreads();
  float kk = 0.f, vv = 0.f;
#pragma unroll
  for (int h = 0; h < 64; ++h) {
    kk = fmaf(hs_s[h], Wbuf[l * 65 + h], kk);
    vv = fmaf(hs_s[h], Wbuf[4224 + l * 65 + h], vv);
  }
  __syncthreads();
  for (int i = 0; i < 64; ++i) Wbuf[i * 65 + l] = Wq[i * 64 + l];
  __syncthreads();
  float qq = 0.f;
#pragma unroll
  for (int h = 0; h < 64; ++h) qq = fmaf(hs_s[h], Wbuf[l * 65 + h], qq);

  float nrm = fmaxf(sqrtf(wave_sum64(kk * kk)), 1e-12f);
  k_tab[tok * 64 + l] = kk / nrm;
  v_tab[tok * 64 + l] = vv;
  q_tab[tok * 64 + l] = qq;
}

// ---------------------------------------------------------------------------
// Kernel B: GV[a][l] = {-G[a][l], v[a][l]} packed float2 (G NEGATED so every
// downstream update is a positive fma); KQ[a][l] = q_a.k_l.
// ---------------------------------------------------------------------------
__global__ __launch_bounds__(64) void build_gram(
    const float* __restrict__ k_tab, const float* __restrict__ q_tab,
    const float* __restrict__ v_tab, float2* __restrict__ GV,
    float* __restrict__ KQ) {
  __shared__ float k_s[4160];
  __shared__ float q_s[64];
  const int a = blockIdx.x;
  const int l = threadIdx.x;
  for (int i = 0; i < 64; ++i) k_s[i * 65 + l] = k_tab[i * 64 + l];
  q_s[l] = q_tab[a * 64 + l];
  __syncthreads();
  float g = 0.f, kq = 0.f;
#pragma unroll
  for (int h = 0; h < 64; ++h) {
    g = fmaf(k_s[a * 65 + h], k_s[l * 65 + h], g);
    kq = fmaf(q_s[h], k_s[l * 65 + h], kq);
  }
  GV[a * 64 + l] = make_float2(-g, v_tab[a * 64 + l]);
  KQ[a * 64 + l] = kq;
}

// ---------------------------------------------------------------------------
// Kernel C: per-batch scan + head. One wave per batch.
// ---------------------------------------------------------------------------
__global__ __launch_bounds__(64, 1) void scan_head(
    const int* __restrict__ seq, const float2* __restrict__ GVg,
    const float* __restrict__ KQ, const float* __restrict__ Wrp,
    const float* __restrict__ brp, const float* __restrict__ Wout,
    const float* __restrict__ bout, float* __restrict__ out) {
  __shared__ float2 GV_s[4160];  // 65 rows of 64 (row 64 = zeros, dummy tok)
  __shared__ float tmp[64];
  const int b = blockIdx.x;
  const int l = threadIdx.x;

#pragma unroll
  for (int i = 0; i < 32; ++i)
    ((float4*)GV_s)[l + 64 * i] = ((const float4*)GVg)[l + 64 * i];
  GV_s[4096 + l] = make_float2(0.f, 0.f);
  __syncthreads();

  const int* tokp = seq + b * 2048;
  const int qt = tokp[2047];  // t=2047 token -> q
  float y = KQ[qt * 64 + l];  // y_a = k_a . q
  float r = 0.f;

  // block tokens: slot j of block nb <-> t = 2047 - (64*nb + j)
  int tokA = (l == 0) ? 64 : tokp[2047 - l];  // block 0 (slot 0 = dummy)
  int tokB = tokp[2047 - 64 - l];             // block 1

  float2 colR[4][4];  // column 4-ring (VGPR, static idx)
  int selS[4][4];     // token lane-select 4-ring (SGPR, static idx)
  float cfb[2][6];    // coef double buffer: [01,02,03,12,13,23]

  // ---- prologue: sels+cols for supersteps 0..2; coefs for superstep 0 ----
#pragma unroll
  for (int g = 0; g < 3; ++g) {
#pragma unroll
    for (int k = 0; k < 4; ++k) {
      selS[g][k] = __builtin_amdgcn_readlane(tokA, 4 * g + k);
      colR[g][k] = GV_s[selS[g][k] * 64 + l];
    }
  }
  {
    const int a1 = selS[0][1] & 63, a2 = selS[0][2] & 63, a3 = selS[0][3] & 63;
    cfb[0][0] = readlane_f(colR[0][0].x, a1);
    cfb[0][1] = readlane_f(colR[0][0].x, a2);
    cfb[0][2] = readlane_f(colR[0][0].x, a3);
    cfb[0][3] = readlane_f(colR[0][1].x, a2);
    cfb[0][4] = readlane_f(colR[0][1].x, a3);
    cfb[0][5] = readlane_f(colR[0][2].x, a3);
  }

  // ---- main loop: 32 blocks x 16 supersteps x 4 steps ----
  for (int blk = 0; blk < 32; ++blk) {
#pragma unroll
    for (int ss = 0; ss < 16; ++ss) {
      const int c0 = ss & 3;         // consume slot
      const int c1 = (ss + 1) & 3;   // coef-source slot
      const int c3 = (ss + 3) & 3;   // prefetch slot
      const int cur = ss & 1;
      const int nxt = cur ^ 1;

      // 1) extract sels + issue col loads for superstep ss+3 (static lanes)
      const int lb = 4 * (ss + 3);
#pragma unroll
      for (int k = 0; k < 4; ++k) {
        selS[c3][k] =
            __builtin_amdgcn_readlane(lb < 64 ? tokA : tokB, (lb & 63) + k);
        colR[c3][k] = GV_s[selS[c3][k] * 64 + l];
      }

      // 2) coefs for superstep ss+1 (cols loaded 2 supersteps ago; off-chain)
      const int a1 = selS[c1][1] & 63, a2 = selS[c1][2] & 63,
                a3 = selS[c1][3] & 63;
      cfb[nxt][0] = readlane_f(colR[c1][0].x, a1);
      cfb[nxt][1] = readlane_f(colR[c1][0].x, a2);
      cfb[nxt][2] = readlane_f(colR[c1][0].x, a3);
      cfb[nxt][3] = readlane_f(colR[c1][1].x, a2);
      cfb[nxt][4] = readlane_f(colR[c1][1].x, a3);
      cfb[nxt][5] = readlane_f(colR[c1][2].x, a3);

      // 3) p gathers: ONE round trip, 4 pipelined readlanes of pre-update y
      const float p0 = readlane_f(y, selS[c0][0] & 63);
      const float p1 = readlane_f(y, selS[c0][1] & 63);
      const float p2 = readlane_f(y, selS[c0][2] & 63);
      const float p3 = readlane_f(y, selS[c0][3] & 63);

      // 4) local 4x4 solve (reference nesting: s0 correction innermost)
      const float s0 = p0;
      const float s1 = fmaf(cfb[cur][0], s0, p1);
      const float s2 = fmaf(cfb[cur][3], s1, fmaf(cfb[cur][1], s0, p2));
      const float s3 = fmaf(
          cfb[cur][5], s2,
          fmaf(cfb[cur][4], s1, fmaf(cfb[cur][2], s0, p3)));

      // 5) y/r updates, sequential step order (bit-identical to reference)
      y = fmaf(s0, colR[c0][0].x, y);
      r = fmaf(s0, colR[c0][0].y, r);
      y = fmaf(s1, colR[c0][1].x, y);
      r = fmaf(s1, colR[c0][1].y, r);
      y = fmaf(s2, colR[c0][2].x, y);
      r = fmaf(s2, colR[c0][2].y, r);
      y = fmaf(s3, colR[c0][3].x, y);
      r = fmaf(s3, colR[c0][3].y, r);
    }
    tokA = tokB;
    tokB = (blk + 2 < 32) ? tokp[2047 - 64 * (blk + 2) - l] : 64;
  }

  // ---- Head: r -> Wrp -> Wout (weights staged padded into GV_s memory) --
  float* Wb = (float*)GV_s;
  tmp[l] = r;
  __syncthreads();
  for (int i = 0; i < 64; ++i) {
    Wb[i * 65 + l] = Wrp[i * 64 + l];
    Wb[4160 + i * 65 + l] = Wout[i * 64 + l];
  }
  __syncthreads();
  float acc = brp[l];
#pragma unroll
  for (int j = 0; j < 64; ++j) acc = fmaf(tmp[j], Wb[l * 65 + j], acc);
  __syncthreads();
  tmp[l] = acc;
  __syncthreads();
  float o = bout[l];
#pragma unroll
  for (int i = 0; i < 64; ++i) o = fmaf(tmp[i], Wb[4160 + l * 65 + i], o);
  out[b * 64 + l] = o;
}

extern "C" void kernel_launch(void* const* d_in, const int* in_sizes, int n_in,
                              void* d_out, int out_size, void* d_ws,
                              size_t ws_size, hipStream_t stream) {
  const int* seq = (const int*)d_in[0];
  const float* embed = (const float*)d_in[1];
  const float* W1 = (const float*)d_in[2];
  const float* b1 = (const float*)d_in[3];
  const float* W2 = (const float*)d_in[4];
  const float* b2 = (const float*)d_in[5];
  const float* gamma = (const float*)d_in[6];
  const float* beta = (const float*)d_in[7];
  const float* Wk = (const float*)d_in[8];
  const float* Wv = (const float*)d_in[9];
  const float* Wq = (const float*)d_in[10];
  const float* Wrp = (const float*)d_in[11];
  const float* brp = (const float*)d_in[12];
  const float* Wout = (const float*)d_in[13];
  const float* bout = (const float*)d_in[14];

  float* wsf = (float*)d_ws;
  float* k_tab = wsf;                   // 4096
  float* v_tab = wsf + 4096;            // 4096
  float* q_tab = wsf + 8192;            // 4096
  float2* GV = (float2*)(wsf + 12288);  // 4096 float2 = 8192 floats
  float* KQ = wsf + 20480;              // 4096

  build_tables<<<64, 64, 0, stream>>>(embed, W1, b1, W2, b2, gamma, beta, Wk,
                                      Wv, Wq, k_tab, v_tab, q_tab);
  build_gram<<<64, 64, 0, stream>>>(k_tab, q_tab, v_tab, GV, KQ);
  scan_head<<<256, 64, 0, stream>>>(seq, GV, KQ, Wrp, brp, Wout, bout,
                                    (float*)d_out);
}